// Round 3
// baseline (239.481 us; speedup 1.0000x reference)
//
#include <hip/hip_runtime.h>
#include <stdint.h>

#define B_ROWS 4096
#define N_ROWS 8192
#define D_DIM  1024
#define BK     64
#define NBLK   32          // 8192 / 256 tile blocks per dim
#define NTRI   528         // 32*33/2 upper-triangular tiles
#define XCDQ   66          // 528 / 8, exact -> bijective XCD swizzle

typedef __attribute__((ext_vector_type(8))) short bf16x8;
typedef __attribute__((ext_vector_type(4))) float f32x4;

// round-to-nearest-even f32 -> bf16
static __device__ __forceinline__ unsigned short f2bf(float f) {
  uint32_t u = __float_as_uint(f);
  u += 0x7fff + ((u >> 16) & 1);
  return (unsigned short)(u >> 16);
}

static __device__ __forceinline__ void async_copy16(const unsigned short* g, unsigned short* l) {
  __builtin_amdgcn_global_load_lds(
      (const __attribute__((address_space(1))) unsigned int*)g,
      (__attribute__((address_space(3))) unsigned int*)l, 16, 0, 0);
}

// raw workgroup barrier: does NOT drain vmcnt (unlike __syncthreads) so
// prefetch global_load_lds stay in flight across it.
static __device__ __forceinline__ void wg_barrier() {
  asm volatile("" ::: "memory");
  __builtin_amdgcn_s_barrier();
  asm volatile("" ::: "memory");
}

// One block per row: L2-normalize, cast to bf16, and zero rowsum.
__global__ __launch_bounds__(256) void normalize_kernel(
    const float* __restrict__ f1, const float* __restrict__ f2,
    unsigned short* __restrict__ F, float* __restrict__ rowsum) {
  const int row = blockIdx.x;
  const int tid = threadIdx.x;
  const float* src = (row < B_ROWS) ? (f1 + (size_t)row * D_DIM)
                                    : (f2 + (size_t)(row - B_ROWS) * D_DIM);
  float4 v = ((const float4*)src)[tid];
  float ss = v.x * v.x + v.y * v.y + v.z * v.z + v.w * v.w;
#pragma unroll
  for (int m = 1; m < 64; m <<= 1) ss += __shfl_xor(ss, m, 64);
  __shared__ float red[4];
  if ((tid & 63) == 0) red[tid >> 6] = ss;
  __syncthreads();
  ss = red[0] + red[1] + red[2] + red[3];
  const float invn = 1.0f / fmaxf(sqrtf(ss), 1e-12f);
  ushort4 o;
  o.x = f2bf(v.x * invn); o.y = f2bf(v.y * invn);
  o.z = f2bf(v.z * invn); o.w = f2bf(v.w * invn);
  ((ushort4*)(F + (size_t)row * D_DIM))[tid] = o;
  if (tid == 0) rowsum[row] = 0.0f;
}

// Fused Gram-GEMM + exp-sum epilogue over UPPER-TRIANGULAR 256x256 tiles.
// 8 waves (2M x 4N), wave tile 128x64 via 8x4 grid of 16x16x32 bf16 MFMA.
// Double-buffered LDS (128 KiB). Counted-vmcnt deep pipeline (T3+T4):
// staging is split into 8-KB quarters (1 global_load_lds per thread each),
// issued 2-3 per phase into the idle buffer; drains are vmcnt(6)/vmcnt(2)
// (never 0 in the main loop), so 2-8 loads always stay in flight.
// In-flight ledger (steady state, per wave, 8 loads/tile):
//   enter tile t:            [Aq1^t, Aq3^t]                      (2)
//   P0 stages Aq0,Aq2,Bq0^t+1  -> 5;  P1 stages Bq1,Bq2,Bq3^t+1 -> 8
//   P1-end vmcnt(6): certifies Aq1^t,Aq3^t  (needed by P2 reads)
//   P2 stages Aq1,Aq3^t+1      -> 8
//   P2-end vmcnt(2): certifies the 6 quarters next tile's P0/P1 reads
// Overwrite safety: each staged quarter's previous-content reads completed
// >= 1 full K-tile before the write is issued.
__global__ __launch_bounds__(512, 2) void simloss_kernel(
    const unsigned short* __restrict__ F, float* __restrict__ rowsum,
    float* __restrict__ pos) {
  __shared__ unsigned short lA[2][256 * BK];   // 64 KiB
  __shared__ unsigned short lB[2][256 * BK];   // 64 KiB

  // bijective XCD swizzle: each XCD gets 66 consecutive triangle ids
  int bid = (blockIdx.x & 7) * XCDQ + (blockIdx.x >> 3);
  int rem = bid;
  int bi = 0;
  while (rem >= NBLK - bi) { rem -= NBLK - bi; ++bi; }
  const int bj = bi + rem;

  const int tid  = threadIdx.x;
  const int lane = tid & 63;
  const int wv   = __builtin_amdgcn_readfirstlane(tid >> 6);
  const int warpRow = wv >> 2;   // 0..1
  const int warpCol = wv & 3;    // 0..3
  const int q   = lane >> 4;
  const int l16 = lane & 15;

  const int iBase = bi * 256;
  const int jBase = bj * 256;
  const unsigned short* __restrict__ GA = F + (size_t)iBase * D_DIM;
  const unsigned short* __restrict__ GB = F + (size_t)jBase * D_DIM;

  f32x4 acc[8][4];
#pragma unroll
  for (int a = 0; a < 8; ++a)
#pragma unroll
    for (int b = 0; b < 4; ++b) acc[a][b] = (f32x4){0.f, 0.f, 0.f, 0.f};

  // operand fragments held across phases (each ds_read once per K-tile)
  bf16x8 aF[4][2];      // current A-half (mh); reloaded at P2
  bf16x8 bF[2][2][2];   // both B-halves [nh][ni][kk2]; loaded P0, P1

  // Stage one 64-row x 64-col quarter (8 KB) of A or B into buffer BUFI.
  // Chunk (QI*512 + tid) holds global [row = QI*64 + tid>>3][col8 ^ (row&7)].
#define STAGE_Q(BUFI, QI, ISB, K0)                                           \
  {                                                                          \
    const int lr   = tid >> 3;                                               \
    const int gcol = (tid & 7) ^ (lr & 7);                                   \
    const size_t goff = (size_t)((QI) * 64 + lr) * D_DIM + (K0) + gcol * 8;  \
    if (ISB) async_copy16(GB + goff, &lB[BUFI][((QI) * 512 + tid) * 8]);     \
    else     async_copy16(GA + goff, &lA[BUFI][((QI) * 512 + tid) * 8]);     \
  }

#define LOAD_A(BUFI, MH)                                                     \
  {                                                                          \
    _Pragma("unroll") for (int kk2 = 0; kk2 < 2; ++kk2) {                    \
      const int cb = kk2 * 4 + q;                                            \
      _Pragma("unroll") for (int mi = 0; mi < 4; ++mi) {                     \
        const int r  = warpRow * 128 + (MH) * 64 + mi * 16 + l16;            \
        const int ch = r * 8 + (cb ^ (r & 7));                               \
        aF[mi][kk2] = *(const bf16x8*)&lA[BUFI][ch * 8];                     \
      }                                                                      \
    }                                                                        \
  }

#define LOAD_B(BUFI, NH)                                                     \
  {                                                                          \
    _Pragma("unroll") for (int kk2 = 0; kk2 < 2; ++kk2) {                    \
      const int cb = kk2 * 4 + q;                                            \
      _Pragma("unroll") for (int ni = 0; ni < 2; ++ni) {                     \
        const int r  = warpCol * 64 + (NH) * 32 + ni * 16 + l16;             \
        const int ch = r * 8 + (cb ^ (r & 7));                               \
        bF[NH][ni][kk2] = *(const bf16x8*)&lB[BUFI][ch * 8];                 \
      }                                                                      \
    }                                                                        \
  }

#define MFMA_Q(MH, NH)                                                       \
  _Pragma("unroll") for (int mi = 0; mi < 4; ++mi)                           \
    _Pragma("unroll") for (int ni = 0; ni < 2; ++ni)                         \
      _Pragma("unroll") for (int kk2 = 0; kk2 < 2; ++kk2)                    \
        acc[(MH) * 4 + mi][(NH) * 2 + ni] =                                  \
            __builtin_amdgcn_mfma_f32_16x16x32_bf16(                         \
                aF[mi][kk2], bF[NH][ni][kk2],                                \
                acc[(MH) * 4 + mi][(NH) * 2 + ni], 0, 0, 0);

  // prologue: stage tile 0 in first-use order, certify all but Aq1/Aq3
  STAGE_Q(0, 0, 0, 0) STAGE_Q(0, 2, 0, 0) STAGE_Q(0, 0, 1, 0)
  STAGE_Q(0, 1, 1, 0) STAGE_Q(0, 2, 1, 0) STAGE_Q(0, 3, 1, 0)
  STAGE_Q(0, 1, 0, 0) STAGE_Q(0, 3, 0, 0)
  asm volatile("s_waitcnt vmcnt(2)" ::: "memory");
  wg_barrier();

#pragma unroll 1
  for (int t = 0; t < 16; ++t) {
    const int p = t & 1;
    const int kn = (t + 1) * BK;
    const bool st = (t < 15);

    // ---- P0: quadrant (0,0) ----
    if (st) { STAGE_Q(p ^ 1, 0, 0, kn) STAGE_Q(p ^ 1, 2, 0, kn) STAGE_Q(p ^ 1, 0, 1, kn) }
    LOAD_A(p, 0) LOAD_B(p, 0)
    wg_barrier();
    __builtin_amdgcn_s_setprio(1);
    MFMA_Q(0, 0)
    __builtin_amdgcn_s_setprio(0);
    wg_barrier();

    // ---- P1: quadrant (0,1) ----
    if (st) { STAGE_Q(p ^ 1, 1, 1, kn) STAGE_Q(p ^ 1, 2, 1, kn) STAGE_Q(p ^ 1, 3, 1, kn) }
    LOAD_B(p, 1)
    wg_barrier();
    __builtin_amdgcn_s_setprio(1);
    MFMA_Q(0, 1)
    __builtin_amdgcn_s_setprio(0);
    if (st) asm volatile("s_waitcnt vmcnt(6)" ::: "memory");
    else    asm volatile("s_waitcnt vmcnt(0)" ::: "memory");
    wg_barrier();

    // ---- P2: quadrants (1,1) + (1,0) merged (32 MFMA) ----
    if (st) { STAGE_Q(p ^ 1, 1, 0, kn) STAGE_Q(p ^ 1, 3, 0, kn) }
    LOAD_A(p, 1)
    wg_barrier();
    __builtin_amdgcn_s_setprio(1);
    MFMA_Q(1, 1)
    MFMA_Q(1, 0)
    __builtin_amdgcn_s_setprio(0);
    if (st) asm volatile("s_waitcnt vmcnt(2)" ::: "memory");
    wg_barrier();
  }
#undef MFMA_Q
#undef LOAD_B
#undef LOAD_A
#undef STAGE_Q

  // ---- epilogue ----
  // sim = 10*dot; e = exp(sim-10) excluding diagonal.
  // Row-reduce -> rowsum[i]; for off-diag tiles also column-reduce -> rowsum[j].
  const bool offdiag = (bi != bj);
  float colAcc[4] = {0.f, 0.f, 0.f, 0.f};

#pragma unroll
  for (int mf = 0; mf < 8; ++mf) {
#pragma unroll
    for (int reg = 0; reg < 4; ++reg) {
      const int i = iBase + warpRow * 128 + (mf >> 2) * 64 + (mf & 3) * 16 + q * 4 + reg;
      float s = 0.0f;
#pragma unroll
      for (int nf = 0; nf < 4; ++nf) {
        const int j = jBase + warpCol * 64 + (nf >> 1) * 32 + (nf & 1) * 16 + l16;
        const float sim = acc[mf][nf][reg] * 10.0f;
        const float e = (j == i) ? 0.0f : __expf(sim - 10.0f);
        s += e;
        colAcc[nf] += e;
        if (i < B_ROWS && j == i + B_ROWS) pos[i] = sim;
      }
      // reduce across the 16 lanes (same q, varying l16) sharing row i
#pragma unroll
      for (int m = 1; m < 16; m <<= 1) s += __shfl_xor(s, m, 64);
      if (l16 == 0) atomicAdd(&rowsum[i], s);
    }
  }

  if (offdiag) {
    // column sums: reduce across quads (lanes sharing l16); q==0 lanes hold
    // per-column totals for j = jBase + warpCol*64 + (nf>>1)*32 + (nf&1)*16 + l16
#pragma unroll
    for (int nf = 0; nf < 4; ++nf) {
      float c = colAcc[nf];
      c += __shfl_xor(c, 16, 64);
      c += __shfl_xor(c, 32, 64);
      if (q == 0) {
        const int j = jBase + warpCol * 64 + (nf >> 1) * 32 + (nf & 1) * 16 + l16;
        atomicAdd(&rowsum[j], c);
      }
    }
  }
}

__global__ __launch_bounds__(1024) void finalize_kernel(
    const float* __restrict__ rowsum, const float* __restrict__ pos,
    float* __restrict__ out) {
  const int tid = threadIdx.x;
  float a = 0.0f;
  for (int i = tid; i < N_ROWS; i += 1024)
    a += logf(rowsum[i]) + 10.0f - pos[i & (B_ROWS - 1)];
#pragma unroll
  for (int m = 1; m < 64; m <<= 1) a += __shfl_xor(a, m, 64);
  __shared__ float red[16];
  if ((tid & 63) == 0) red[tid >> 6] = a;
  __syncthreads();
  if (tid == 0) {
    float t = 0.0f;
#pragma unroll
    for (int w = 0; w < 16; ++w) t += red[w];
    out[0] = t * (1.0f / N_ROWS);
  }
}

extern "C" void kernel_launch(void* const* d_in, const int* in_sizes, int n_in,
                              void* d_out, int out_size, void* d_ws, size_t ws_size,
                              hipStream_t stream) {
  const float* f1 = (const float*)d_in[0];
  const float* f2 = (const float*)d_in[1];
  unsigned short* F = (unsigned short*)d_ws;                          // 16 MiB bf16 normalized features
  float* rowsum = (float*)((char*)d_ws + (size_t)N_ROWS * D_DIM * 2); // 32 KiB
  float* pos    = rowsum + N_ROWS;                                    // 16 KiB used (i < B_ROWS)
  float* out    = (float*)d_out;

  hipLaunchKernelGGL(normalize_kernel, dim3(N_ROWS), dim3(256), 0, stream, f1, f2, F, rowsum);
  hipLaunchKernelGGL(simloss_kernel, dim3(NTRI), dim3(512), 0, stream, F, rowsum, pos);
  hipLaunchKernelGGL(finalize_kernel, dim3(1), dim3(1024), 0, stream, rowsum, pos, out);
}

// Round 4
// 203.266 us; speedup vs baseline: 1.1782x; 1.1782x over previous
//
#include <hip/hip_runtime.h>
#include <stdint.h>

#define B_ROWS 4096
#define N_ROWS 8192
#define D_DIM  1024
#define BK     64
#define NBLK   32          // 8192 / 256 tile blocks per dim
#define NTRI   528         // 32*33/2 upper-triangular tiles
#define XCDQ   66          // 528 / 8, exact -> bijective XCD chunk

typedef __attribute__((ext_vector_type(8))) short bf16x8;
typedef __attribute__((ext_vector_type(4))) float f32x4;

// round-to-nearest-even f32 -> bf16
static __device__ __forceinline__ unsigned short f2bf(float f) {
  uint32_t u = __float_as_uint(f);
  u += 0x7fff + ((u >> 16) & 1);
  return (unsigned short)(u >> 16);
}

static __device__ __forceinline__ void async_copy16(const unsigned short* g, unsigned short* l) {
  __builtin_amdgcn_global_load_lds(
      (const __attribute__((address_space(1))) unsigned int*)g,
      (__attribute__((address_space(3))) unsigned int*)l, 16, 0, 0);
}

// raw workgroup barrier: does NOT drain vmcnt (unlike __syncthreads) so
// prefetch global_load_lds stay in flight across it.
static __device__ __forceinline__ void wg_barrier() {
  asm volatile("" ::: "memory");
  __builtin_amdgcn_s_barrier();
  asm volatile("" ::: "memory");
}

// One block per row: L2-normalize, cast to bf16, and zero rowsum.
__global__ __launch_bounds__(256) void normalize_kernel(
    const float* __restrict__ f1, const float* __restrict__ f2,
    unsigned short* __restrict__ F, float* __restrict__ rowsum) {
  const int row = blockIdx.x;
  const int tid = threadIdx.x;
  const float* src = (row < B_ROWS) ? (f1 + (size_t)row * D_DIM)
                                    : (f2 + (size_t)(row - B_ROWS) * D_DIM);
  float4 v = ((const float4*)src)[tid];
  float ss = v.x * v.x + v.y * v.y + v.z * v.z + v.w * v.w;
#pragma unroll
  for (int m = 1; m < 64; m <<= 1) ss += __shfl_xor(ss, m, 64);
  __shared__ float red[4];
  if ((tid & 63) == 0) red[tid >> 6] = ss;
  __syncthreads();
  ss = red[0] + red[1] + red[2] + red[3];
  const float invn = 1.0f / fmaxf(sqrtf(ss), 1e-12f);
  ushort4 o;
  o.x = f2bf(v.x * invn); o.y = f2bf(v.y * invn);
  o.z = f2bf(v.z * invn); o.w = f2bf(v.w * invn);
  ((ushort4*)(F + (size_t)row * D_DIM))[tid] = o;
  if (tid == 0) rowsum[row] = 0.0f;
}

// Fused Gram-GEMM + exp-sum epilogue over UPPER-TRIANGULAR 256x256 tiles.
// 8 waves (2M x 4N), wave tile 128x64 via 8x4 grid of 16x16x32 bf16 MFMA.
// Double-buffered LDS (128 KiB). Per K-tile, 4 quadrant phases ordered
// (0,0)->(0,1)->(1,1)->(1,0) so each operand fragment is ds_read ONCE.
// Block->tile mapping uses SUPERTILE-COLUMN scheduling for L2 locality:
// 4x4 supertiles, column-major (SJ outer) so each column's 4 B-panels
// (2 MB) stay L2-resident across the whole column; within a supertile,
// 4-tile groups share one bj panel. 528 = 8 XCDs x 66 slots exactly.
__global__ __launch_bounds__(512, 2) void simloss_kernel(
    const unsigned short* __restrict__ F, float* __restrict__ rowsum,
    float* __restrict__ pos) {
  __shared__ unsigned short lA[2][256 * BK];   // 64 KiB
  __shared__ unsigned short lB[2][256 * BK];   // 64 KiB

  // --- L2-locality supertile scheduling ---
  // chunked bijective XCD remap: XCD x works slots [66x, 66x+66)
  int s = (blockIdx.x & 7) * XCDQ + (blockIdx.x >> 3);
  // supertile column SJ (col SJ holds 16*SJ + 10 tiles; sum = 528)
  int SJ = 0;
  for (;;) { const int c = 16 * SJ + 10; if (s < c) break; s -= c; ++SJ; }
  // supertile row SI within column (off-diag supertiles: 16 tiles each)
  int SI = 0;
  while (SI < SJ && s >= 16) { s -= 16; ++SI; }
  int di, dj;
  if (SI < SJ) {            // off-diagonal supertile: dj-major 4-tile groups
    dj = s >> 2; di = s & 3;
  } else {                  // diagonal supertile: upper 10 tiles, dj-major
    dj = 0; while (s > dj) { s -= (dj + 1); ++dj; } di = s;
  }
  const int bi = SI * 4 + di;
  const int bj = SJ * 4 + dj;

  const int tid  = threadIdx.x;
  const int lane = tid & 63;
  const int wv   = __builtin_amdgcn_readfirstlane(tid >> 6);
  const int warpRow = wv >> 2;   // 0..1
  const int warpCol = wv & 3;    // 0..3
  const int q   = lane >> 4;
  const int l16 = lane & 15;

  const int iBase = bi * 256;
  const int jBase = bj * 256;
  const unsigned short* __restrict__ GA = F + (size_t)iBase * D_DIM;
  const unsigned short* __restrict__ GB = F + (size_t)jBase * D_DIM;

  f32x4 acc[8][4];
#pragma unroll
  for (int a = 0; a < 8; ++a)
#pragma unroll
    for (int b = 0; b < 4; ++b) acc[a][b] = (f32x4){0.f, 0.f, 0.f, 0.f};

  // operand fragments held across phases (loaded once per K-tile)
  bf16x8 aF[4][2];      // current A-half (mh), reloaded at phase (1,1)
  bf16x8 bF[2][2][2];   // both B-halves [nh][ni][kk2], loaded phases 1,2

  // LDS chunk lc (16B) of a buffer holds global [row = lc>>3][col8 = (lc&7) ^ (row&7)]
#define STAGE(BUFI, K0)                                                      \
  {                                                                          \
    _Pragma("unroll") for (int it = 0; it < 4; ++it) {                       \
      const int lc   = it * 512 + tid;                                       \
      const int row  = lc >> 3;                                              \
      const int gcol = (lc & 7) ^ (row & 7);                                 \
      const size_t goff = (size_t)row * D_DIM + (K0) + gcol * 8;             \
      async_copy16(GA + goff, &lA[BUFI][lc * 8]);                            \
      async_copy16(GB + goff, &lB[BUFI][lc * 8]);                            \
    }                                                                        \
  }

  // One quadrant phase: optional A/B fragment loads, barrier, 16 MFMA,
  // optional vmcnt drain, barrier.
#define PHASE(BUFI, MH, NH, LOADA, LOADB, DODRAIN_)                          \
  {                                                                          \
    if (LOADA) {                                                             \
      _Pragma("unroll") for (int kk2 = 0; kk2 < 2; ++kk2) {                  \
        const int cb = kk2 * 4 + q;                                          \
        _Pragma("unroll") for (int mi = 0; mi < 4; ++mi) {                   \
          const int r  = warpRow * 128 + (MH) * 64 + mi * 16 + l16;          \
          const int ch = r * 8 + (cb ^ (r & 7));                             \
          aF[mi][kk2] = *(const bf16x8*)&lA[BUFI][ch * 8];                   \
        }                                                                    \
      }                                                                      \
    }                                                                        \
    if (LOADB) {                                                             \
      _Pragma("unroll") for (int kk2 = 0; kk2 < 2; ++kk2) {                  \
        const int cb = kk2 * 4 + q;                                          \
        _Pragma("unroll") for (int ni = 0; ni < 2; ++ni) {                   \
          const int r  = warpCol * 64 + (NH) * 32 + ni * 16 + l16;           \
          const int ch = r * 8 + (cb ^ (r & 7));                             \
          bF[NH][ni][kk2] = *(const bf16x8*)&lB[BUFI][ch * 8];               \
        }                                                                    \
      }                                                                      \
    }                                                                        \
    wg_barrier();                                                            \
    __builtin_amdgcn_s_setprio(1);                                           \
    _Pragma("unroll") for (int mi = 0; mi < 4; ++mi)                         \
      _Pragma("unroll") for (int ni = 0; ni < 2; ++ni)                       \
        _Pragma("unroll") for (int kk2 = 0; kk2 < 2; ++kk2)                  \
          acc[(MH) * 4 + mi][(NH) * 2 + ni] =                                \
              __builtin_amdgcn_mfma_f32_16x16x32_bf16(                       \
                  aF[mi][kk2], bF[NH][ni][kk2],                              \
                  acc[(MH) * 4 + mi][(NH) * 2 + ni], 0, 0, 0);               \
    __builtin_amdgcn_s_setprio(0);                                           \
    if (DODRAIN_) asm volatile("s_waitcnt vmcnt(0)" ::: "memory");           \
    wg_barrier();                                                            \
  }

#define KTILE(BUFI, DOSTAGE, K0NEXT, DODRAIN)                                \
  {                                                                          \
    if (DOSTAGE) STAGE((BUFI) ^ 1, (K0NEXT));                                \
    PHASE(BUFI, 0, 0, true,  true,  false)                                   \
    PHASE(BUFI, 0, 1, false, true,  false)                                   \
    PHASE(BUFI, 1, 1, true,  false, false)                                   \
    PHASE(BUFI, 1, 0, false, false, (DODRAIN))                               \
  }

  // prologue: stage K-tile 0, drain, barrier
  STAGE(0, 0);
  asm volatile("s_waitcnt vmcnt(0)" ::: "memory");
  wg_barrier();

#pragma unroll 1
  for (int t2 = 0; t2 < 8; ++t2) {
    const int k0 = t2 * 128;
    const bool last = (t2 == 7);
    KTILE(0, true, k0 + 64, true);
    KTILE(1, !last, k0 + 128, !last);
  }
#undef KTILE
#undef PHASE
#undef STAGE

  // ---- epilogue ----
  // sim = 10*dot; e = exp(sim-10) excluding diagonal.
  // Row-reduce -> rowsum[i]; for off-diag tiles also column-reduce -> rowsum[j].
  const bool offdiag = (bi != bj);
  float colAcc[4] = {0.f, 0.f, 0.f, 0.f};

#pragma unroll
  for (int mf = 0; mf < 8; ++mf) {
#pragma unroll
    for (int reg = 0; reg < 4; ++reg) {
      const int i = iBase + warpRow * 128 + (mf >> 2) * 64 + (mf & 3) * 16 + q * 4 + reg;
      float s2 = 0.0f;
#pragma unroll
      for (int nf = 0; nf < 4; ++nf) {
        const int j = jBase + warpCol * 64 + (nf >> 1) * 32 + (nf & 1) * 16 + l16;
        const float sim = acc[mf][nf][reg] * 10.0f;
        const float e = (j == i) ? 0.0f : __expf(sim - 10.0f);
        s2 += e;
        colAcc[nf] += e;
        if (i < B_ROWS && j == i + B_ROWS) pos[i] = sim;
      }
      // reduce across the 16 lanes (same q, varying l16) sharing row i
#pragma unroll
      for (int m = 1; m < 16; m <<= 1) s2 += __shfl_xor(s2, m, 64);
      if (l16 == 0) atomicAdd(&rowsum[i], s2);
    }
  }

  if (offdiag) {
    // column sums: reduce across quads (lanes sharing l16); q==0 lanes hold
    // per-column totals for j = jBase + warpCol*64 + (nf>>1)*32 + (nf&1)*16 + l16
#pragma unroll
    for (int nf = 0; nf < 4; ++nf) {
      float c = colAcc[nf];
      c += __shfl_xor(c, 16, 64);
      c += __shfl_xor(c, 32, 64);
      if (q == 0) {
        const int j = jBase + warpCol * 64 + (nf >> 1) * 32 + (nf & 1) * 16 + l16;
        atomicAdd(&rowsum[j], c);
      }
    }
  }
}

__global__ __launch_bounds__(1024) void finalize_kernel(
    const float* __restrict__ rowsum, const float* __restrict__ pos,
    float* __restrict__ out) {
  const int tid = threadIdx.x;
  float a = 0.0f;
  for (int i = tid; i < N_ROWS; i += 1024)
    a += logf(rowsum[i]) + 10.0f - pos[i & (B_ROWS - 1)];
#pragma unroll
  for (int m = 1; m < 64; m <<= 1) a += __shfl_xor(a, m, 64);
  __shared__ float red[16];
  if ((tid & 63) == 0) red[tid >> 6] = a;
  __syncthreads();
  if (tid == 0) {
    float t = 0.0f;
#pragma unroll
    for (int w = 0; w < 16; ++w) t += red[w];
    out[0] = t * (1.0f / N_ROWS);
  }
}

extern "C" void kernel_launch(void* const* d_in, const int* in_sizes, int n_in,
                              void* d_out, int out_size, void* d_ws, size_t ws_size,
                              hipStream_t stream) {
  const float* f1 = (const float*)d_in[0];
  const float* f2 = (const float*)d_in[1];
  unsigned short* F = (unsigned short*)d_ws;                          // 16 MiB bf16 normalized features
  float* rowsum = (float*)((char*)d_ws + (size_t)N_ROWS * D_DIM * 2); // 32 KiB
  float* pos    = rowsum + N_ROWS;                                    // 16 KiB used (i < B_ROWS)
  float* out    = (float*)d_out;

  hipLaunchKernelGGL(normalize_kernel, dim3(N_ROWS), dim3(256), 0, stream, f1, f2, F, rowsum);
  hipLaunchKernelGGL(simloss_kernel, dim3(NTRI), dim3(512), 0, stream, F, rowsum, pos);
  hipLaunchKernelGGL(finalize_kernel, dim3(1), dim3(1024), 0, stream, rowsum, pos, out);
}

// Round 5
// 176.843 us; speedup vs baseline: 1.3542x; 1.1494x over previous
//
#include <hip/hip_runtime.h>
#include <stdint.h>

#define B_ROWS 4096
#define N_ROWS 8192
#define D_DIM  1024
#define NBLK   64          // 8192 / 128 tile blocks per dim
#define NTRI   2080        // 64*65/2 upper-triangular tiles
#define XCDQ   260         // 2080 / 8, exact -> bijective XCD chunk

typedef __attribute__((ext_vector_type(8))) short bf16x8;
typedef __attribute__((ext_vector_type(4))) float f32x4;

// round-to-nearest-even f32 -> bf16
static __device__ __forceinline__ unsigned short f2bf(float f) {
  uint32_t u = __float_as_uint(f);
  u += 0x7fff + ((u >> 16) & 1);
  return (unsigned short)(u >> 16);
}

static __device__ __forceinline__ void async_copy16(const unsigned short* g, unsigned short* l) {
  __builtin_amdgcn_global_load_lds(
      (const __attribute__((address_space(1))) unsigned int*)g,
      (__attribute__((address_space(3))) unsigned int*)l, 16, 0, 0);
}

// raw workgroup barrier: does NOT drain vmcnt (unlike __syncthreads) so
// prefetch global_load_lds stay in flight across it.
static __device__ __forceinline__ void wg_barrier() {
  asm volatile("" ::: "memory");
  __builtin_amdgcn_s_barrier();
  asm volatile("" ::: "memory");
}

// One block per row: L2-normalize, cast to bf16, and zero rowsum.
__global__ __launch_bounds__(256) void normalize_kernel(
    const float* __restrict__ f1, const float* __restrict__ f2,
    unsigned short* __restrict__ F, float* __restrict__ rowsum) {
  const int row = blockIdx.x;
  const int tid = threadIdx.x;
  const float* src = (row < B_ROWS) ? (f1 + (size_t)row * D_DIM)
                                    : (f2 + (size_t)(row - B_ROWS) * D_DIM);
  float4 v = ((const float4*)src)[tid];
  float ss = v.x * v.x + v.y * v.y + v.z * v.z + v.w * v.w;
#pragma unroll
  for (int m = 1; m < 64; m <<= 1) ss += __shfl_xor(ss, m, 64);
  __shared__ float red[4];
  if ((tid & 63) == 0) red[tid >> 6] = ss;
  __syncthreads();
  ss = red[0] + red[1] + red[2] + red[3];
  const float invn = 1.0f / fmaxf(sqrtf(ss), 1e-12f);
  ushort4 o;
  o.x = f2bf(v.x * invn); o.y = f2bf(v.y * invn);
  o.z = f2bf(v.z * invn); o.w = f2bf(v.w * invn);
  ((ushort4*)(F + (size_t)row * D_DIM))[tid] = o;
  if (tid == 0) rowsum[row] = 0.0f;
}

// Fused Gram-GEMM + exp-sum epilogue over UPPER-TRIANGULAR 128x128 tiles.
// m97-geometry for CO-RESIDENCY: 4 waves (2x2, 64x64 each), BK=32,
// double-buffered 32 KiB LDS, ~3 blocks/CU so cross-block TLP hides the
// per-K-step vmcnt drain (m114 mechanism). One raw barrier + one vmcnt(0)
// per K-step. Supertile-column schedule (8x8-tile supertiles, column-major)
// keeps each column's B-panels (2 MB) L2-resident; 2080 = 8 XCDs x 260.
__global__ __launch_bounds__(256, 3) void simloss_kernel(
    const unsigned short* __restrict__ F, float* __restrict__ rowsum,
    float* __restrict__ pos) {
  __shared__ unsigned short lA[2][128 * 32];   // 2 x 8 KiB
  __shared__ unsigned short lB[2][128 * 32];   // 2 x 8 KiB

  // --- L2-locality supertile scheduling (8x8 tiles per supertile) ---
  // chunked bijective XCD remap: XCD x works slots [260x, 260x+260)
  int s = (blockIdx.x & 7) * XCDQ + (blockIdx.x >> 3);
  // supertile column SJ: col SJ holds 64*SJ + 36 tiles (sum = 2080)
  int SJ = 0;
  for (;;) { const int c = 64 * SJ + 36; if (s < c) break; s -= c; ++SJ; }
  int SI = 0;
  while (SI < SJ && s >= 64) { s -= 64; ++SI; }
  int di, dj;
  if (SI < SJ) {            // off-diagonal supertile: dj-major 8-tile groups
    dj = s >> 3; di = s & 7;
  } else {                  // diagonal supertile: upper 36 tiles, dj-major
    dj = 0; while (s > dj) { s -= (dj + 1); ++dj; } di = s;
  }
  const int bi = SI * 8 + di;
  const int bj = SJ * 8 + dj;

  const int tid  = threadIdx.x;
  const int lane = tid & 63;
  const int wv   = __builtin_amdgcn_readfirstlane(tid >> 6);
  const int waveRow = wv >> 1;   // 0..1
  const int waveCol = wv & 1;    // 0..1
  const int q   = lane >> 4;
  const int l16 = lane & 15;

  const int iBase = bi * 128;
  const int jBase = bj * 128;
  const unsigned short* __restrict__ GA = F + (size_t)iBase * D_DIM;
  const unsigned short* __restrict__ GB = F + (size_t)jBase * D_DIM;

  f32x4 acc[4][4];
#pragma unroll
  for (int a = 0; a < 4; ++a)
#pragma unroll
    for (int b = 0; b < 4; ++b) acc[a][b] = (f32x4){0.f, 0.f, 0.f, 0.f};

  // Panel row r (128 rows x 32 cols bf16) = 4 chunks of 16 B.
  // LDS chunk lc = r*4 + c holds global chunk  c ^ ((r>>1)&3)  (bank-spread
  // XOR; pre-swizzled global source, linear LDS dest, same XOR on read).
#define STAGE(BUFI, K0)                                                      \
  {                                                                          \
    _Pragma("unroll") for (int it = 0; it < 2; ++it) {                       \
      const int lc = it * 256 + tid;                                         \
      const int r  = lc >> 2;                                                \
      const int gc = (lc & 3) ^ ((r >> 1) & 3);                              \
      const size_t goff = (size_t)r * D_DIM + (K0) + gc * 8;                 \
      async_copy16(GA + goff, &lA[BUFI][lc * 8]);                            \
      async_copy16(GB + goff, &lB[BUFI][lc * 8]);                            \
    }                                                                        \
  }

  // One K-step (K=32): 8 ds_read_b128 + 16 MFMA per wave.
#define STEP(BUFI)                                                           \
  {                                                                          \
    bf16x8 af[4], bfr[4];                                                    \
    _Pragma("unroll") for (int mi = 0; mi < 4; ++mi) {                       \
      const int r  = waveRow * 64 + mi * 16 + l16;                           \
      const int ch = r * 4 + (q ^ ((r >> 1) & 3));                           \
      af[mi] = *(const bf16x8*)&lA[BUFI][ch * 8];                            \
    }                                                                        \
    _Pragma("unroll") for (int ni = 0; ni < 4; ++ni) {                       \
      const int r  = waveCol * 64 + ni * 16 + l16;                           \
      const int ch = r * 4 + (q ^ ((r >> 1) & 3));                           \
      bfr[ni] = *(const bf16x8*)&lB[BUFI][ch * 8];                           \
    }                                                                        \
    _Pragma("unroll") for (int mi = 0; mi < 4; ++mi)                         \
      _Pragma("unroll") for (int ni = 0; ni < 4; ++ni)                       \
        acc[mi][ni] = __builtin_amdgcn_mfma_f32_16x16x32_bf16(               \
            af[mi], bfr[ni], acc[mi][ni], 0, 0, 0);                          \
  }

  // prologue: stage K-step 0 into buffer 0
  STAGE(0, 0)
  asm volatile("s_waitcnt vmcnt(0)" ::: "memory");
  wg_barrier();

#pragma unroll 1
  for (int t2 = 0; t2 < 16; ++t2) {
    const int k0 = t2 * 64;
    const bool last = (t2 == 15);
    // sub-step A: reads buf0 @k0, prefetches buf1 @k0+32
    STAGE(1, k0 + 32)
    STEP(0)
    asm volatile("s_waitcnt vmcnt(0)" ::: "memory");
    wg_barrier();
    // sub-step B: reads buf1 @k0+32, prefetches buf0 @k0+64
    if (!last) STAGE(0, k0 + 64)
    STEP(1)
    if (!last) asm volatile("s_waitcnt vmcnt(0)" ::: "memory");
    wg_barrier();
  }
#undef STEP
#undef STAGE

  // ---- epilogue ----
  // sim = 10*dot; e = exp(sim-10) excluding diagonal.
  // Row-reduce -> rowsum[i]; for off-diag tiles also column-reduce -> rowsum[j].
  const bool offdiag = (bi != bj);
  float colAcc[4] = {0.f, 0.f, 0.f, 0.f};

#pragma unroll
  for (int mi = 0; mi < 4; ++mi) {
#pragma unroll
    for (int reg = 0; reg < 4; ++reg) {
      const int i = iBase + waveRow * 64 + mi * 16 + q * 4 + reg;
      float s2 = 0.0f;
#pragma unroll
      for (int ni = 0; ni < 4; ++ni) {
        const int j = jBase + waveCol * 64 + ni * 16 + l16;
        const float sim = acc[mi][ni][reg] * 10.0f;
        const float e = (j == i) ? 0.0f : __expf(sim - 10.0f);
        s2 += e;
        colAcc[ni] += e;
        if (i < B_ROWS && j == i + B_ROWS) pos[i] = sim;
      }
      // reduce across the 16 lanes (same q, varying l16) sharing row i
#pragma unroll
      for (int m = 1; m < 16; m <<= 1) s2 += __shfl_xor(s2, m, 64);
      if (l16 == 0) atomicAdd(&rowsum[i], s2);
    }
  }

  if (offdiag) {
    // column sums: reduce across quads (lanes sharing l16); q==0 lanes hold
    // per-column totals for j = jBase + waveCol*64 + ni*16 + l16
#pragma unroll
    for (int ni = 0; ni < 4; ++ni) {
      float c = colAcc[ni];
      c += __shfl_xor(c, 16, 64);
      c += __shfl_xor(c, 32, 64);
      if (q == 0) {
        const int j = jBase + waveCol * 64 + ni * 16 + l16;
        atomicAdd(&rowsum[j], c);
      }
    }
  }
}

__global__ __launch_bounds__(1024) void finalize_kernel(
    const float* __restrict__ rowsum, const float* __restrict__ pos,
    float* __restrict__ out) {
  const int tid = threadIdx.x;
  float a = 0.0f;
  for (int i = tid; i < N_ROWS; i += 1024)
    a += logf(rowsum[i]) + 10.0f - pos[i & (B_ROWS - 1)];
#pragma unroll
  for (int m = 1; m < 64; m <<= 1) a += __shfl_xor(a, m, 64);
  __shared__ float red[16];
  if ((tid & 63) == 0) red[tid >> 6] = a;
  __syncthreads();
  if (tid == 0) {
    float t = 0.0f;
#pragma unroll
    for (int w = 0; w < 16; ++w) t += red[w];
    out[0] = t * (1.0f / N_ROWS);
  }
}

extern "C" void kernel_launch(void* const* d_in, const int* in_sizes, int n_in,
                              void* d_out, int out_size, void* d_ws, size_t ws_size,
                              hipStream_t stream) {
  const float* f1 = (const float*)d_in[0];
  const float* f2 = (const float*)d_in[1];
  unsigned short* F = (unsigned short*)d_ws;                          // 16 MiB bf16 normalized features
  float* rowsum = (float*)((char*)d_ws + (size_t)N_ROWS * D_DIM * 2); // 32 KiB
  float* pos    = rowsum + N_ROWS;                                    // 16 KiB used (i < B_ROWS)
  float* out    = (float*)d_out;

  hipLaunchKernelGGL(normalize_kernel, dim3(N_ROWS), dim3(256), 0, stream, f1, f2, F, rowsum);
  hipLaunchKernelGGL(simloss_kernel, dim3(NTRI), dim3(256), 0, stream, F, rowsum, pos);
  hipLaunchKernelGGL(finalize_kernel, dim3(1), dim3(1024), 0, stream, rowsum, pos, out);
}